// Round 1
// baseline (2687.213 us; speedup 1.0000x reference)
//
#include <hip/hip_runtime.h>
#include <hip/hip_bf16.h>

#define EMBED   1024
#define HEADS   16
#define HDIM    64
#define SEQ     2048
#define BATCH   4
#define QKV_LD  3072   // 3*EMBED

// ---------------------------------------------------------------------------
// Tiled fp32 GEMM: C[M,N] = A[M,K] @ B[K,N] + bias[N]
// BM=BN=64, BK=16, 256 threads, 4x4 per-thread microtile.
// ---------------------------------------------------------------------------
template<int BM, int BN, int BK>
__global__ __launch_bounds__(256) void gemm_bias(const float* __restrict__ A,
                                                 const float* __restrict__ B,
                                                 const float* __restrict__ bias,
                                                 float* __restrict__ C,
                                                 int M, int N, int K) {
    __shared__ float As[BK][BM + 4];
    __shared__ float Bs[BK][BN + 4];

    const int tid = threadIdx.x;
    const int tx = tid & 15;   // 0..15 -> 4 cols each
    const int ty = tid >> 4;   // 0..15 -> 4 rows each
    const int row0 = blockIdx.y * BM;
    const int col0 = blockIdx.x * BN;

    float c[4][4] = {};

    for (int k0 = 0; k0 < K; k0 += BK) {
        // Load A tile (BM x BK) into As[kk][m]
        #pragma unroll
        for (int i = 0; i < (BM * BK) / 256; ++i) {
            int idx = i * 256 + tid;
            int kk  = idx & (BK - 1);
            int m   = idx / BK;
            As[kk][m] = A[(size_t)(row0 + m) * K + k0 + kk];
        }
        // Load B tile (BK x BN) into Bs[kk][n]
        #pragma unroll
        for (int i = 0; i < (BK * BN) / 256; ++i) {
            int idx = i * 256 + tid;
            int n   = idx & (BN - 1);
            int kk  = idx / BN;
            Bs[kk][n] = B[(size_t)(k0 + kk) * N + col0 + n];
        }
        __syncthreads();

        #pragma unroll
        for (int kk = 0; kk < BK; ++kk) {
            float4 a4 = *(const float4*)&As[kk][ty * 4];
            float4 b4 = *(const float4*)&Bs[kk][tx * 4];
            float av[4] = {a4.x, a4.y, a4.z, a4.w};
            float bv[4] = {b4.x, b4.y, b4.z, b4.w};
            #pragma unroll
            for (int i = 0; i < 4; ++i)
                #pragma unroll
                for (int j = 0; j < 4; ++j)
                    c[i][j] += av[i] * bv[j];
        }
        __syncthreads();
    }

    #pragma unroll
    for (int i = 0; i < 4; ++i) {
        int m = row0 + ty * 4 + i;
        #pragma unroll
        for (int j = 0; j < 4; ++j) {
            int n = col0 + tx * 4 + j;
            C[(size_t)m * N + n] = c[i][j] + bias[n];
        }
    }
}

// ---------------------------------------------------------------------------
// Flash-style fp32 attention.
// Grid: (SEQ/32, BATCH*HEADS). Block: 256 threads.
// Each block: 32 q-rows of one (b,h). Iterate 32-key tiles with online softmax.
// Thread t: q-row r = t>>3 (full row cached in regs), output cols d = (t&7)*8..+8.
// S entries: thread computes j = (t&7) + 8*jj, jj=0..3; row-reduce via shfl_xor
// within the aligned 8-lane group that shares row r.
// ---------------------------------------------------------------------------
__global__ __launch_bounds__(256) void attn_kernel(const float* __restrict__ qkv,
                                                   float* __restrict__ attout) {
    const int bh = blockIdx.y;           // 0..63
    const int b  = bh >> 4;
    const int h  = bh & 15;
    const int qt = blockIdx.x;           // 0..SEQ/32-1
    const int tid = threadIdx.x;
    const int r   = tid >> 3;            // 0..31 q-row within tile
    const int c8  = tid & 7;             // 0..7
    const float scale = 0.125f;          // 1/sqrt(64)

    __shared__ float qs[32][HDIM + 4];
    __shared__ float ks[32][HDIM + 4];
    __shared__ float vs[32][HDIM + 4];
    __shared__ float ps[32][36];

    const float* qbase = qkv + (size_t)(b * SEQ) * QKV_LD + h * HDIM;
    const float* kbase = qbase + EMBED;
    const float* vbase = qbase + 2 * EMBED;

    // Load q tile (32 rows x 64) coalesced
    #pragma unroll
    for (int i = 0; i < 2; ++i) {
        int f4  = i * 256 + tid;         // 0..511
        int row = f4 >> 4;               // 0..31
        int c4  = f4 & 15;               // 0..15
        *(float4*)&qs[row][c4 * 4] =
            *(const float4*)(qbase + (size_t)(qt * 32 + row) * QKV_LD + c4 * 4);
    }
    __syncthreads();

    float qreg[HDIM];
    #pragma unroll
    for (int d = 0; d < HDIM; ++d) qreg[d] = qs[r][d];

    float acc[8] = {};
    float m_r = -1e30f, l_r = 0.f;

    for (int kt = 0; kt < SEQ / 32; ++kt) {
        __syncthreads();   // prev PV done before overwriting ks/vs
        #pragma unroll
        for (int i = 0; i < 2; ++i) {
            int f4  = i * 256 + tid;
            int row = f4 >> 4;
            int c4  = f4 & 15;
            size_t goff = (size_t)(kt * 32 + row) * QKV_LD + c4 * 4;
            *(float4*)&ks[row][c4 * 4] = *(const float4*)(kbase + goff);
            *(float4*)&vs[row][c4 * 4] = *(const float4*)(vbase + goff);
        }
        __syncthreads();

        // S[r][j] for j = c8 + 8*jj
        float s[4] = {};
        #pragma unroll
        for (int d4 = 0; d4 < 16; ++d4) {
            #pragma unroll
            for (int jj = 0; jj < 4; ++jj) {
                const float4 kv = *(const float4*)&ks[c8 + 8 * jj][d4 * 4];
                s[jj] += qreg[d4*4+0]*kv.x + qreg[d4*4+1]*kv.y +
                         qreg[d4*4+2]*kv.z + qreg[d4*4+3]*kv.w;
            }
        }
        #pragma unroll
        for (int jj = 0; jj < 4; ++jj) s[jj] *= scale;

        // online softmax: row max over 32 entries (4 local + 8-lane group)
        float pmax = fmaxf(fmaxf(s[0], s[1]), fmaxf(s[2], s[3]));
        pmax = fmaxf(pmax, __shfl_xor(pmax, 1));
        pmax = fmaxf(pmax, __shfl_xor(pmax, 2));
        pmax = fmaxf(pmax, __shfl_xor(pmax, 4));

        float m_new = fmaxf(m_r, pmax);
        float alpha = __expf(m_r - m_new);
        float p[4], psum = 0.f;
        #pragma unroll
        for (int jj = 0; jj < 4; ++jj) { p[jj] = __expf(s[jj] - m_new); psum += p[jj]; }
        psum += __shfl_xor(psum, 1);
        psum += __shfl_xor(psum, 2);
        psum += __shfl_xor(psum, 4);
        l_r = l_r * alpha + psum;
        m_r = m_new;

        #pragma unroll
        for (int dd = 0; dd < 8; ++dd) acc[dd] *= alpha;

        #pragma unroll
        for (int jj = 0; jj < 4; ++jj) ps[r][c8 + 8 * jj] = p[jj];
        __syncthreads();

        // PV: acc[dd] += sum_j P[r][j] * V[j][d0+dd]
        const int d0 = c8 * 8;
        #pragma unroll
        for (int j = 0; j < 32; ++j) {
            float pv = ps[r][j];
            float4 v0 = *(const float4*)&vs[j][d0];
            float4 v1 = *(const float4*)&vs[j][d0 + 4];
            acc[0] += pv * v0.x; acc[1] += pv * v0.y;
            acc[2] += pv * v0.z; acc[3] += pv * v0.w;
            acc[4] += pv * v1.x; acc[5] += pv * v1.y;
            acc[6] += pv * v1.z; acc[7] += pv * v1.w;
        }
    }

    // epilogue: attout[b, n, h*64 + d] = acc/l
    float inv_l = 1.0f / l_r;
    int n = qt * 32 + r;
    float* o = attout + (size_t)(b * SEQ + n) * EMBED + h * HDIM + c8 * 8;
    float4 o0 = {acc[0]*inv_l, acc[1]*inv_l, acc[2]*inv_l, acc[3]*inv_l};
    float4 o1 = {acc[4]*inv_l, acc[5]*inv_l, acc[6]*inv_l, acc[7]*inv_l};
    *(float4*)(o)     = o0;
    *(float4*)(o + 4) = o1;
}

// ---------------------------------------------------------------------------
extern "C" void kernel_launch(void* const* d_in, const int* in_sizes, int n_in,
                              void* d_out, int out_size, void* d_ws, size_t ws_size,
                              hipStream_t stream) {
    const float* x      = (const float*)d_in[0];   // [4,2048,1024]
    const float* W_qkv  = (const float*)d_in[1];   // [1024,3072]
    const float* b_qkv  = (const float*)d_in[2];   // [3072]
    const float* W_proj = (const float*)d_in[3];   // [1024,1024]
    const float* b_proj = (const float*)d_in[4];   // [1024]
    float* out = (float*)d_out;                    // [4,2048,1024]

    const int M = BATCH * SEQ;                     // 8192

    float* qkv    = (float*)d_ws;                  // M x 3072 fp32 (96 MB)
    float* attout = qkv + (size_t)M * QKV_LD;      // M x 1024 fp32 (32 MB)

    dim3 blk(256);

    // 1) qkv = x @ W_qkv + b_qkv
    gemm_bias<64, 64, 16><<<dim3(QKV_LD / 64, M / 64), blk, 0, stream>>>(
        x, W_qkv, b_qkv, qkv, M, QKV_LD, EMBED);

    // 2) flash attention per (b,h)
    attn_kernel<<<dim3(SEQ / 32, BATCH * HEADS), blk, 0, stream>>>(qkv, attout);

    // 3) out = attout @ W_proj + b_proj
    gemm_bias<64, 64, 16><<<dim3(EMBED / 64, M / 64), blk, 0, stream>>>(
        attout, W_proj, b_proj, out, M, EMBED, EMBED);
}

// Round 2
// 387.030 us; speedup vs baseline: 6.9432x; 6.9432x over previous
//
#include <hip/hip_runtime.h>

#define EMBED   1024
#define HEADS   16
#define HDIM    64
#define SEQ     2048
#define BATCH   4
#define QKV_LD  3072

typedef __attribute__((ext_vector_type(8))) short short8v;
typedef __attribute__((ext_vector_type(4))) float floatx4;

__device__ __forceinline__ unsigned short f2bf(float f) {
    unsigned int u = __builtin_bit_cast(unsigned int, f);
    u += 0x7FFFu + ((u >> 16) & 1u);
    return (unsigned short)(u >> 16);
}
__device__ __forceinline__ float bf2f(unsigned short h) {
    unsigned int u = ((unsigned int)h) << 16;
    return __builtin_bit_cast(float, u);
}

// ---------------------------------------------------------------------------
// x fp32 -> bf16, 4 elems/thread
// ---------------------------------------------------------------------------
__global__ __launch_bounds__(256) void cast_f32_bf16(const float* __restrict__ in,
                                                     unsigned short* __restrict__ out) {
    int i = blockIdx.x * 256 + threadIdx.x;
    float4 v = ((const float4*)in)[i];
    unsigned short o[4] = { f2bf(v.x), f2bf(v.y), f2bf(v.z), f2bf(v.w) };
    ((uint2*)out)[i] = *(uint2*)o;
}

// ---------------------------------------------------------------------------
// fp32 [K][N] -> bf16 [N][K] (64x64 tiles)
// ---------------------------------------------------------------------------
__global__ __launch_bounds__(256) void transpose_cast(const float* __restrict__ in,
                                                      unsigned short* __restrict__ out,
                                                      int K, int N) {
    __shared__ float T[64][65];
    const int k0 = blockIdx.y * 64, n0 = blockIdx.x * 64;
    const int t = threadIdx.x;
    #pragma unroll
    for (int i = 0; i < 4; ++i) {
        int s = i * 256 + t;               // 0..1023
        int k = s >> 4, c4 = s & 15;
        float4 v = *(const float4*)(in + (size_t)(k0 + k) * N + n0 + c4 * 4);
        T[k][c4*4+0] = v.x; T[k][c4*4+1] = v.y; T[k][c4*4+2] = v.z; T[k][c4*4+3] = v.w;
    }
    __syncthreads();
    const int n = t >> 2, kc = (t & 3) * 16;
    unsigned short tmp[16];
    #pragma unroll
    for (int j = 0; j < 16; ++j) tmp[j] = f2bf(T[kc + j][n]);
    *(short8v*)(out + (size_t)(n0 + n) * K + k0 + kc)     = *(short8v*)&tmp[0];
    *(short8v*)(out + (size_t)(n0 + n) * K + k0 + kc + 8) = *(short8v*)&tmp[8];
}

// ---------------------------------------------------------------------------
// V slice of qkv_b -> Vt [bh][d=64][seq=2048] bf16
// ---------------------------------------------------------------------------
__global__ __launch_bounds__(256) void vt_kernel(const unsigned short* __restrict__ qkvb,
                                                 unsigned short* __restrict__ vt) {
    const int bh = blockIdx.y, b = bh >> 4, h = bh & 15;
    const int n0 = blockIdx.x * 64;
    const int t = threadIdx.x;
    __shared__ __align__(16) unsigned short T[64][72];
    #pragma unroll
    for (int i = 0; i < 2; ++i) {
        int s = i * 256 + t;
        int n = s >> 3, c = s & 7;
        short8v v = *(const short8v*)(qkvb + (size_t)(b*SEQ + n0 + n) * QKV_LD + 2*EMBED + h*HDIM + c*8);
        *(short8v*)&T[n][c*8] = v;
    }
    __syncthreads();
    #pragma unroll
    for (int i = 0; i < 2; ++i) {
        int s = i * 256 + t;
        int d = s >> 3, c = s & 7;
        unsigned short tmp[8];
        #pragma unroll
        for (int j = 0; j < 8; ++j) tmp[j] = T[c*8 + j][d];
        *(short8v*)(vt + ((size_t)bh * HDIM + d) * SEQ + n0 + c*8) = *(short8v*)&tmp[0];
    }
}

// ---------------------------------------------------------------------------
// bf16 MFMA GEMM: C[M,N] = A[M,K] @ BT[N,K]^T + bias.  128x128x32 tile, 4 waves.
// LDS padded [128][40] (80B rows) -> conflict-free ds_read_b128 fragments.
// ---------------------------------------------------------------------------
template<bool OUT_BF16>
__global__ __launch_bounds__(256) void gemm_bf16(const unsigned short* __restrict__ A,
                                                 const unsigned short* __restrict__ BT,
                                                 const float* __restrict__ bias,
                                                 void* __restrict__ Cout,
                                                 int M, int N, int K) {
    __shared__ __align__(16) unsigned short As[128 * 40];
    __shared__ __align__(16) unsigned short Bs[128 * 40];
    const int tid = threadIdx.x;
    const int lane = tid & 63;
    const int w = tid >> 6;
    const int wm = w >> 1, wn = w & 1;
    const int lq = lane & 15, lg = lane >> 4;
    const int row0 = blockIdx.y * 128;
    const int col0 = blockIdx.x * 128;

    floatx4 acc[4][4];
    #pragma unroll
    for (int i = 0; i < 4; ++i)
        #pragma unroll
        for (int j = 0; j < 4; ++j)
            acc[i][j] = (floatx4){0.f, 0.f, 0.f, 0.f};

    for (int k0 = 0; k0 < K; k0 += 32) {
        __syncthreads();
        #pragma unroll
        for (int i = 0; i < 2; ++i) {
            int s = i * 256 + tid;
            int r = s >> 2, c = s & 3;
            short8v va = *(const short8v*)(A  + (size_t)(row0 + r) * K + k0 + c * 8);
            short8v vb = *(const short8v*)(BT + (size_t)(col0 + r) * K + k0 + c * 8);
            *(short8v*)(As + r * 40 + c * 8) = va;
            *(short8v*)(Bs + r * 40 + c * 8) = vb;
        }
        __syncthreads();

        short8v af[4], bf[4];
        #pragma unroll
        for (int mi = 0; mi < 4; ++mi)
            af[mi] = *(const short8v*)(As + (wm*64 + mi*16 + lq) * 40 + lg * 8);
        #pragma unroll
        for (int ni = 0; ni < 4; ++ni)
            bf[ni] = *(const short8v*)(Bs + (wn*64 + ni*16 + lq) * 40 + lg * 8);
        #pragma unroll
        for (int mi = 0; mi < 4; ++mi)
            #pragma unroll
            for (int ni = 0; ni < 4; ++ni)
                acc[mi][ni] = __builtin_amdgcn_mfma_f32_16x16x32_bf16(af[mi], bf[ni], acc[mi][ni], 0, 0, 0);
    }

    #pragma unroll
    for (int mi = 0; mi < 4; ++mi) {
        #pragma unroll
        for (int ni = 0; ni < 4; ++ni) {
            int col = col0 + wn*64 + ni*16 + lq;
            float bv = bias[col];
            #pragma unroll
            for (int r = 0; r < 4; ++r) {
                int row = row0 + wm*64 + mi*16 + lg*4 + r;
                float v = acc[mi][ni][r] + bv;
                if constexpr (OUT_BF16)
                    ((unsigned short*)Cout)[(size_t)row * N + col] = f2bf(v);
                else
                    ((float*)Cout)[(size_t)row * N + col] = v;
            }
        }
    }
}

// ---------------------------------------------------------------------------
// MFMA flash attention.  Grid (16 q-blocks, 64 bh), 256 threads = 4 waves.
// Wave w: 32 q-rows.  KV tile = 64.  S = mfma(Q, K); softmax fp32 per-lane
// (C-layout rows = lg*4+r, cols = lq); P -> per-wave LDS -> PV A-frags;
// V from transposed Vt tile.  All LDS rows padded to 72 elems (144 B).
// ---------------------------------------------------------------------------
__global__ __launch_bounds__(256) void attn_mfma(const unsigned short* __restrict__ qkvb,
                                                 const unsigned short* __restrict__ vt,
                                                 unsigned short* __restrict__ attout) {
    const int bh = blockIdx.y, b = bh >> 4, h = bh & 15;
    const int qb = blockIdx.x;
    const int tid = threadIdx.x;
    const int lane = tid & 63;
    const int w = tid >> 6;
    const int lq = lane & 15, lg = lane >> 4;

    __shared__ __align__(16) unsigned short Ks[64 * 72];
    __shared__ __align__(16) unsigned short Vs[64 * 72];   // [d][kv]
    __shared__ __align__(16) unsigned short Ps[4][32 * 72];

    // Q fragments (held in registers for all 32 KV tiles), pre-scaled by 1/8
    short8v qf[2][2];
    const unsigned short* qbase = qkvb + (size_t)(b*SEQ + qb*128 + w*32) * QKV_LD + h*HDIM;
    #pragma unroll
    for (int m = 0; m < 2; ++m)
        #pragma unroll
        for (int ks = 0; ks < 2; ++ks) {
            qf[m][ks] = *(const short8v*)(qbase + (size_t)(m*16 + lq) * QKV_LD + ks*32 + lg*8);
            #pragma unroll
            for (int j = 0; j < 8; ++j) {
                float f = bf2f((unsigned short)qf[m][ks][j]) * 0.125f;  // exact (pow2)
                qf[m][ks][j] = (short)f2bf(f);
            }
        }

    floatx4 o[2][4];
    float mr[2][4], lsum[2][4];
    #pragma unroll
    for (int m = 0; m < 2; ++m)
        #pragma unroll
        for (int r = 0; r < 4; ++r) {
            mr[m][r] = -1e30f; lsum[m][r] = 0.f;
            if (r < 4) {}
        }
    #pragma unroll
    for (int m = 0; m < 2; ++m)
        #pragma unroll
        for (int dt = 0; dt < 4; ++dt)
            o[m][dt] = (floatx4){0.f, 0.f, 0.f, 0.f};

    const unsigned short* kbase = qkvb + (size_t)(b*SEQ) * QKV_LD + EMBED + h*HDIM;
    const unsigned short* vbase = vt + (size_t)bh * HDIM * SEQ;
    unsigned short* ps = &Ps[w][0];

    for (int kt = 0; kt < SEQ / 64; ++kt) {
        __syncthreads();
        #pragma unroll
        for (int i = 0; i < 2; ++i) {
            int s = i * 256 + tid;
            int r = s >> 3, c = s & 7;
            short8v kv = *(const short8v*)(kbase + (size_t)(kt*64 + r) * QKV_LD + c*8);
            short8v vv = *(const short8v*)(vbase + (size_t)r * SEQ + kt*64 + c*8);
            *(short8v*)(Ks + r*72 + c*8) = kv;
            *(short8v*)(Vs + r*72 + c*8) = vv;
        }
        __syncthreads();

        // ---- S = Q @ K^T ----
        short8v kf[4][2];
        #pragma unroll
        for (int n = 0; n < 4; ++n)
            #pragma unroll
            for (int ks = 0; ks < 2; ++ks)
                kf[n][ks] = *(const short8v*)(Ks + (n*16 + lq)*72 + ks*32 + lg*8);

        floatx4 sacc[2][4];
        #pragma unroll
        for (int m = 0; m < 2; ++m)
            #pragma unroll
            for (int n = 0; n < 4; ++n) {
                sacc[m][n] = (floatx4){0.f, 0.f, 0.f, 0.f};
                sacc[m][n] = __builtin_amdgcn_mfma_f32_16x16x32_bf16(qf[m][0], kf[n][0], sacc[m][n], 0, 0, 0);
                sacc[m][n] = __builtin_amdgcn_mfma_f32_16x16x32_bf16(qf[m][1], kf[n][1], sacc[m][n], 0, 0, 0);
            }

        // ---- online softmax (rows = m*16 + lg*4 + r, cols across lq group) ----
        #pragma unroll
        for (int m = 0; m < 2; ++m) {
            #pragma unroll
            for (int r = 0; r < 4; ++r) {
                float pm = sacc[m][0][r];
                pm = fmaxf(pm, sacc[m][1][r]);
                pm = fmaxf(pm, sacc[m][2][r]);
                pm = fmaxf(pm, sacc[m][3][r]);
                pm = fmaxf(pm, __shfl_xor(pm, 1));
                pm = fmaxf(pm, __shfl_xor(pm, 2));
                pm = fmaxf(pm, __shfl_xor(pm, 4));
                pm = fmaxf(pm, __shfl_xor(pm, 8));
                float mnew = fmaxf(mr[m][r], pm);
                float alpha = __expf(mr[m][r] - mnew);
                mr[m][r] = mnew;
                float psum = 0.f;
                #pragma unroll
                for (int n = 0; n < 4; ++n) {
                    float p = __expf(sacc[m][n][r] - mnew);
                    sacc[m][n][r] = p;
                    psum += p;
                }
                psum += __shfl_xor(psum, 1);
                psum += __shfl_xor(psum, 2);
                psum += __shfl_xor(psum, 4);
                psum += __shfl_xor(psum, 8);
                lsum[m][r] = lsum[m][r] * alpha + psum;
                #pragma unroll
                for (int dt = 0; dt < 4; ++dt) o[m][dt][r] *= alpha;
            }
        }

        // ---- P -> LDS (per-wave region, no barrier needed) ----
        #pragma unroll
        for (int m = 0; m < 2; ++m)
            #pragma unroll
            for (int n = 0; n < 4; ++n)
                #pragma unroll
                for (int r = 0; r < 4; ++r)
                    ps[(m*16 + lg*4 + r) * 72 + n*16 + lq] = f2bf(sacc[m][n][r]);

        // ---- O += P @ V ----
        short8v pf[2][2];
        #pragma unroll
        for (int m = 0; m < 2; ++m)
            #pragma unroll
            for (int ks = 0; ks < 2; ++ks)
                pf[m][ks] = *(const short8v*)(ps + (m*16 + lq)*72 + ks*32 + lg*8);
        #pragma unroll
        for (int dt = 0; dt < 4; ++dt)
            #pragma unroll
            for (int ks = 0; ks < 2; ++ks) {
                short8v vf = *(const short8v*)(Vs + (dt*16 + lq)*72 + ks*32 + lg*8);
                #pragma unroll
                for (int m = 0; m < 2; ++m)
                    o[m][dt] = __builtin_amdgcn_mfma_f32_16x16x32_bf16(pf[m][ks], vf, o[m][dt], 0, 0, 0);
            }
    }

    // ---- epilogue: O / l -> bf16 attout ----
    #pragma unroll
    for (int m = 0; m < 2; ++m)
        #pragma unroll
        for (int dt = 0; dt < 4; ++dt)
            #pragma unroll
            for (int r = 0; r < 4; ++r) {
                float v = o[m][dt][r] / lsum[m][r];
                int row = qb*128 + w*32 + m*16 + lg*4 + r;
                int col = h*HDIM + dt*16 + lq;
                attout[(size_t)(b*SEQ + row) * EMBED + col] = f2bf(v);
            }
}

// ---------------------------------------------------------------------------
extern "C" void kernel_launch(void* const* d_in, const int* in_sizes, int n_in,
                              void* d_out, int out_size, void* d_ws, size_t ws_size,
                              hipStream_t stream) {
    const float* x      = (const float*)d_in[0];
    const float* W_qkv  = (const float*)d_in[1];
    const float* b_qkv  = (const float*)d_in[2];
    const float* W_proj = (const float*)d_in[3];
    const float* b_proj = (const float*)d_in[4];
    float* out = (float*)d_out;

    const int M = BATCH * SEQ;   // 8192

    char* ws = (char*)d_ws;
    unsigned short* x_b    = (unsigned short*)(ws);                 // 16 MB
    unsigned short* wqkvT  = (unsigned short*)(ws + 16777216);      // 6 MB
    unsigned short* wprojT = (unsigned short*)(ws + 23068672);      // 2 MB
    unsigned short* qkv_b  = (unsigned short*)(ws + 25165824);      // 48 MB
    unsigned short* vt_b   = (unsigned short*)(ws + 75497472);      // 16 MB
    unsigned short* att_b  = (unsigned short*)(ws + 92274688);      // 16 MB

    cast_f32_bf16<<<dim3((M * EMBED) / 1024), 256, 0, stream>>>(x, x_b);
    transpose_cast<<<dim3(QKV_LD / 64, EMBED / 64), 256, 0, stream>>>(W_qkv, wqkvT, EMBED, QKV_LD);
    transpose_cast<<<dim3(EMBED / 64, EMBED / 64), 256, 0, stream>>>(W_proj, wprojT, EMBED, EMBED);

    gemm_bf16<true><<<dim3(QKV_LD / 128, M / 128), 256, 0, stream>>>(
        x_b, wqkvT, b_qkv, qkv_b, M, QKV_LD, EMBED);

    vt_kernel<<<dim3(SEQ / 64, BATCH * HEADS), 256, 0, stream>>>(qkv_b, vt_b);

    attn_mfma<<<dim3(SEQ / 128, BATCH * HEADS), 256, 0, stream>>>(qkv_b, vt_b, att_b);

    gemm_bf16<false><<<dim3(EMBED / 128, M / 128), 256, 0, stream>>>(
        att_b, wprojT, b_proj, out, M, EMBED, EMBED);
}

// Round 3
// 254.731 us; speedup vs baseline: 10.5492x; 1.5194x over previous
//
#include <hip/hip_runtime.h>

#define EMBED   1024
#define HEADS   16
#define HDIM    64
#define SEQ     2048
#define BATCH   4
#define QKV_LD  3072

typedef __attribute__((ext_vector_type(8))) short short8v;
typedef __attribute__((ext_vector_type(4))) float floatx4;
typedef __attribute__((ext_vector_type(4))) unsigned int uint4v;

// log2(e)/8 : folded into Q so S comes out in base-2 units
#define QSCALE 0.18033688011112042f

__device__ __forceinline__ unsigned short f2bf(float f) {
    unsigned int u = __builtin_bit_cast(unsigned int, f);
    u += 0x7FFFu + ((u >> 16) & 1u);
    return (unsigned short)(u >> 16);
}

__device__ __forceinline__ float fast_exp2(float x) {
    float r;
    asm("v_exp_f32 %0, %1" : "=v"(r) : "v"(x));
    return r;
}
__device__ __forceinline__ unsigned int cvt_pk_bf16(float lo, float hi) {
    unsigned int r;
    asm("v_cvt_pk_bf16_f32 %0, %1, %2" : "=v"(r) : "v"(lo), "v"(hi));
    return r;
}

// ---------------------------------------------------------------------------
__global__ __launch_bounds__(256) void cast_f32_bf16(const float* __restrict__ in,
                                                     unsigned short* __restrict__ out) {
    int i = blockIdx.x * 256 + threadIdx.x;
    float4 v = ((const float4*)in)[i];
    unsigned short o[4] = { f2bf(v.x), f2bf(v.y), f2bf(v.z), f2bf(v.w) };
    ((uint2*)out)[i] = *(uint2*)o;
}

// ---------------------------------------------------------------------------
__global__ __launch_bounds__(256) void transpose_cast(const float* __restrict__ in,
                                                      unsigned short* __restrict__ out,
                                                      int K, int N) {
    __shared__ float T[64][65];
    const int k0 = blockIdx.y * 64, n0 = blockIdx.x * 64;
    const int t = threadIdx.x;
    #pragma unroll
    for (int i = 0; i < 4; ++i) {
        int s = i * 256 + t;
        int k = s >> 4, c4 = s & 15;
        float4 v = *(const float4*)(in + (size_t)(k0 + k) * N + n0 + c4 * 4);
        T[k][c4*4+0] = v.x; T[k][c4*4+1] = v.y; T[k][c4*4+2] = v.z; T[k][c4*4+3] = v.w;
    }
    __syncthreads();
    const int n = t >> 2, kc = (t & 3) * 16;
    unsigned short tmp[16];
    #pragma unroll
    for (int j = 0; j < 16; ++j) tmp[j] = f2bf(T[kc + j][n]);
    *(short8v*)(out + (size_t)(n0 + n) * K + k0 + kc)     = *(short8v*)&tmp[0];
    *(short8v*)(out + (size_t)(n0 + n) * K + k0 + kc + 8) = *(short8v*)&tmp[8];
}

// ---------------------------------------------------------------------------
__global__ __launch_bounds__(256) void vt_kernel(const unsigned short* __restrict__ qkvb,
                                                 unsigned short* __restrict__ vt) {
    const int bh = blockIdx.y, b = bh >> 4, h = bh & 15;
    const int n0 = blockIdx.x * 64;
    const int t = threadIdx.x;
    __shared__ __align__(16) unsigned short T[64][72];
    #pragma unroll
    for (int i = 0; i < 2; ++i) {
        int s = i * 256 + t;
        int n = s >> 3, c = s & 7;
        short8v v = *(const short8v*)(qkvb + (size_t)(b*SEQ + n0 + n) * QKV_LD + 2*EMBED + h*HDIM + c*8);
        *(short8v*)&T[n][c*8] = v;
    }
    __syncthreads();
    #pragma unroll
    for (int i = 0; i < 2; ++i) {
        int s = i * 256 + t;
        int d = s >> 3, c = s & 7;
        unsigned short tmp[8];
        #pragma unroll
        for (int j = 0; j < 8; ++j) tmp[j] = T[c*8 + j][d];
        *(short8v*)(vt + ((size_t)bh * HDIM + d) * SEQ + n0 + c*8) = *(short8v*)&tmp[0];
    }
}

// ---------------------------------------------------------------------------
// bf16 MFMA GEMM, 128x128x32 tile, 4 waves.  SCALE_Q: multiply cols < EMBED
// (the Q third of qkv) by QSCALE in the epilogue (exp2-fold for attention).
// ---------------------------------------------------------------------------
template<bool OUT_BF16, bool SCALE_Q>
__global__ __launch_bounds__(256) void gemm_bf16(const unsigned short* __restrict__ A,
                                                 const unsigned short* __restrict__ BT,
                                                 const float* __restrict__ bias,
                                                 void* __restrict__ Cout,
                                                 int M, int N, int K) {
    __shared__ __align__(16) unsigned short As[128 * 40];
    __shared__ __align__(16) unsigned short Bs[128 * 40];
    const int tid = threadIdx.x;
    const int lane = tid & 63;
    const int w = tid >> 6;
    const int wm = w >> 1, wn = w & 1;
    const int lq = lane & 15, lg = lane >> 4;
    const int row0 = blockIdx.y * 128;
    const int col0 = blockIdx.x * 128;

    floatx4 acc[4][4];
    #pragma unroll
    for (int i = 0; i < 4; ++i)
        #pragma unroll
        for (int j = 0; j < 4; ++j)
            acc[i][j] = (floatx4){0.f, 0.f, 0.f, 0.f};

    for (int k0 = 0; k0 < K; k0 += 32) {
        __syncthreads();
        #pragma unroll
        for (int i = 0; i < 2; ++i) {
            int s = i * 256 + tid;
            int r = s >> 2, c = s & 3;
            short8v va = *(const short8v*)(A  + (size_t)(row0 + r) * K + k0 + c * 8);
            short8v vb = *(const short8v*)(BT + (size_t)(col0 + r) * K + k0 + c * 8);
            *(short8v*)(As + r * 40 + c * 8) = va;
            *(short8v*)(Bs + r * 40 + c * 8) = vb;
        }
        __syncthreads();

        short8v af[4], bf[4];
        #pragma unroll
        for (int mi = 0; mi < 4; ++mi)
            af[mi] = *(const short8v*)(As + (wm*64 + mi*16 + lq) * 40 + lg * 8);
        #pragma unroll
        for (int ni = 0; ni < 4; ++ni)
            bf[ni] = *(const short8v*)(Bs + (wn*64 + ni*16 + lq) * 40 + lg * 8);
        __builtin_amdgcn_s_setprio(1);
        #pragma unroll
        for (int mi = 0; mi < 4; ++mi)
            #pragma unroll
            for (int ni = 0; ni < 4; ++ni)
                acc[mi][ni] = __builtin_amdgcn_mfma_f32_16x16x32_bf16(af[mi], bf[ni], acc[mi][ni], 0, 0, 0);
        __builtin_amdgcn_s_setprio(0);
    }

    #pragma unroll
    for (int mi = 0; mi < 4; ++mi) {
        #pragma unroll
        for (int ni = 0; ni < 4; ++ni) {
            int col = col0 + wn*64 + ni*16 + lq;
            float bv = bias[col];
            #pragma unroll
            for (int r = 0; r < 4; ++r) {
                int row = row0 + wm*64 + mi*16 + lg*4 + r;
                float v = acc[mi][ni][r] + bv;
                if constexpr (SCALE_Q) { if (col < EMBED) v *= QSCALE; }
                if constexpr (OUT_BF16)
                    ((unsigned short*)Cout)[(size_t)row * N + col] = f2bf(v);
                else
                    ((float*)Cout)[(size_t)row * N + col] = v;
            }
        }
    }
}

// ---------------------------------------------------------------------------
// MFMA flash attention, swapped-QK^T softmax.
// Grid (16 q-blocks, 64 bh), 256 threads = 4 waves, 32 q-rows/wave.
// S^T = mfma(K, Q): lane owns q-col lq; k rows n*16+lg*4+r.
// Row stats lane-local + 2 shfl_xor (16,32).  P packed in-lane via
// v_cvt_pk_bf16_f32 into u32 LDS [kpair][q] stride 37.  O normal layout.
// Defer-max: skip rescale unless max grew > 8 (base-2 units).
// ---------------------------------------------------------------------------
__global__ __launch_bounds__(256) void attn_mfma(const unsigned short* __restrict__ qkvb,
                                                 const unsigned short* __restrict__ vt,
                                                 unsigned short* __restrict__ attout) {
    const int bh = blockIdx.y, b = bh >> 4, h = bh & 15;
    const int qb = blockIdx.x;
    const int tid = threadIdx.x;
    const int lane = tid & 63;
    const int w = tid >> 6;
    const int lq = lane & 15, lg = lane >> 4;

    __shared__ __align__(16) unsigned short Ks[64 * 72];
    __shared__ __align__(16) unsigned short Vs[64 * 72];     // [d][kv]
    __shared__ unsigned int Pp[4][32 * 37];                  // per-wave [kpair][q]

    unsigned int* Pw = &Pp[w][0];

    // Q fragments (pre-scaled by QSCALE inside the QKV GEMM)
    short8v qf[2][2];
    const unsigned short* qbase = qkvb + (size_t)(b*SEQ + qb*128 + w*32) * QKV_LD + h*HDIM;
    #pragma unroll
    for (int m = 0; m < 2; ++m)
        #pragma unroll
        for (int ks = 0; ks < 2; ++ks)
            qf[m][ks] = *(const short8v*)(qbase + (size_t)(m*16 + lq) * QKV_LD + ks*32 + lg*8);

    floatx4 o[2][4];
    #pragma unroll
    for (int m = 0; m < 2; ++m)
        #pragma unroll
        for (int dt = 0; dt < 4; ++dt)
            o[m][dt] = (floatx4){0.f, 0.f, 0.f, 0.f};
    float mr[2] = { -1e30f, -1e30f };
    float lsum[2] = { 0.f, 0.f };

    const unsigned short* kbase = qkvb + (size_t)(b*SEQ) * QKV_LD + EMBED + h*HDIM;
    const unsigned short* vbase = vt + (size_t)bh * HDIM * SEQ;

    // staging pattern: thread covers (row=s>>3, col8=s&7) for s = tid, tid+256
    const int sr0 = tid >> 3,         sc0 = tid & 7;
    const int sr1 = (256 + tid) >> 3, sc1 = tid & 7;

    // prefetch tile 0
    short8v rk0 = *(const short8v*)(kbase + (size_t)sr0 * QKV_LD + sc0*8);
    short8v rk1 = *(const short8v*)(kbase + (size_t)sr1 * QKV_LD + sc1*8);
    short8v rv0 = *(const short8v*)(vbase + (size_t)sr0 * SEQ + sc0*8);
    short8v rv1 = *(const short8v*)(vbase + (size_t)sr1 * SEQ + sc1*8);

    const int NT = SEQ / 64;
    for (int kt = 0; kt < NT; ++kt) {
        __syncthreads();   // previous tile's LDS consumers done
        *(short8v*)(Ks + sr0*72 + sc0*8) = rk0;
        *(short8v*)(Ks + sr1*72 + sc1*8) = rk1;
        *(short8v*)(Vs + sr0*72 + sc0*8) = rv0;
        *(short8v*)(Vs + sr1*72 + sc1*8) = rv1;
        __syncthreads();

        // issue next tile's loads (latency hides under compute)
        if (kt + 1 < NT) {
            const unsigned short* kb = kbase + (size_t)(kt + 1) * 64 * QKV_LD;
            const unsigned short* vb = vbase + (kt + 1) * 64;
            rk0 = *(const short8v*)(kb + (size_t)sr0 * QKV_LD + sc0*8);
            rk1 = *(const short8v*)(kb + (size_t)sr1 * QKV_LD + sc1*8);
            rv0 = *(const short8v*)(vb + (size_t)sr0 * SEQ + sc0*8);
            rv1 = *(const short8v*)(vb + (size_t)sr1 * SEQ + sc1*8);
        }

        // ---- S^T = K @ Q^T : sacc[m][n][r] = S[k = n*16+lg*4+r][q = m*16+lq]
        floatx4 sacc[2][4];
        #pragma unroll
        for (int n = 0; n < 4; ++n) {
            short8v kf0 = *(const short8v*)(Ks + (n*16 + lq)*72 + lg*8);
            short8v kf1 = *(const short8v*)(Ks + (n*16 + lq)*72 + 32 + lg*8);
            __builtin_amdgcn_s_setprio(1);
            #pragma unroll
            for (int m = 0; m < 2; ++m) {
                floatx4 z = (floatx4){0.f, 0.f, 0.f, 0.f};
                z = __builtin_amdgcn_mfma_f32_16x16x32_bf16(kf0, qf[m][0], z, 0, 0, 0);
                sacc[m][n] = __builtin_amdgcn_mfma_f32_16x16x32_bf16(kf1, qf[m][1], z, 0, 0, 0);
            }
            __builtin_amdgcn_s_setprio(0);
        }

        // ---- row max (lane-local 16 + lg-group reduce) ----
        float pm[2];
        #pragma unroll
        for (int m = 0; m < 2; ++m) {
            float v = fmaxf(fmaxf(sacc[m][0][0], sacc[m][0][1]),
                            fmaxf(sacc[m][0][2], sacc[m][0][3]));
            #pragma unroll
            for (int n = 1; n < 4; ++n) {
                v = fmaxf(v, fmaxf(fmaxf(sacc[m][n][0], sacc[m][n][1]),
                                   fmaxf(sacc[m][n][2], sacc[m][n][3])));
            }
            v = fmaxf(v, __shfl_xor(v, 16));
            v = fmaxf(v, __shfl_xor(v, 32));
            pm[m] = v;
        }

        // ---- defer-max rescale ----
        int need = (pm[0] > mr[0] + 8.f) | (pm[1] > mr[1] + 8.f);
        if (__any(need)) {
            #pragma unroll
            for (int m = 0; m < 2; ++m) {
                float mnew = fmaxf(mr[m], pm[m]);
                float alpha = fast_exp2(mr[m] - mnew);
                mr[m] = mnew;
                lsum[m] *= alpha;
                #pragma unroll
                for (int r = 0; r < 4; ++r) {
                    float a = __shfl(alpha, lg*4 + r);
                    #pragma unroll
                    for (int dt = 0; dt < 4; ++dt) o[m][dt][r] *= a;
                }
            }
        }

        // ---- P = exp2(S - m), sum, pack, stash in LDS ----
        #pragma unroll
        for (int m = 0; m < 2; ++m) {
            float psum = 0.f;
            #pragma unroll
            for (int n = 0; n < 4; ++n) {
                float p0 = fast_exp2(sacc[m][n][0] - mr[m]);
                float p1 = fast_exp2(sacc[m][n][1] - mr[m]);
                float p2 = fast_exp2(sacc[m][n][2] - mr[m]);
                float p3 = fast_exp2(sacc[m][n][3] - mr[m]);
                psum += (p0 + p1) + (p2 + p3);
                unsigned int k01 = cvt_pk_bf16(p0, p1);
                unsigned int k23 = cvt_pk_bf16(p2, p3);
                Pw[(n*8 + lg*2 + 0)*37 + m*16 + lq] = k01;
                Pw[(n*8 + lg*2 + 1)*37 + m*16 + lq] = k23;
            }
            psum += __shfl_xor(psum, 16);
            psum += __shfl_xor(psum, 32);
            lsum[m] += psum;
        }

        // ---- O += P @ V ----
        short8v af[2][2];
        #pragma unroll
        for (int m = 0; m < 2; ++m)
            #pragma unroll
            for (int ks = 0; ks < 2; ++ks) {
                uint4v t;
                #pragma unroll
                for (int i = 0; i < 4; ++i)
                    t[i] = Pw[(ks*16 + lg*4 + i)*37 + m*16 + lq];
                af[m][ks] = __builtin_bit_cast(short8v, t);
            }
        #pragma unroll
        for (int dt = 0; dt < 4; ++dt) {
            #pragma unroll
            for (int ks = 0; ks < 2; ++ks) {
                short8v vf = *(const short8v*)(Vs + (dt*16 + lq)*72 + ks*32 + lg*8);
                __builtin_amdgcn_s_setprio(1);
                #pragma unroll
                for (int m = 0; m < 2; ++m)
                    o[m][dt] = __builtin_amdgcn_mfma_f32_16x16x32_bf16(af[m][ks], vf, o[m][dt], 0, 0, 0);
                __builtin_amdgcn_s_setprio(0);
            }
        }
    }

    // ---- epilogue ----
    float linv[2][4];
    #pragma unroll
    for (int m = 0; m < 2; ++m)
        #pragma unroll
        for (int r = 0; r < 4; ++r)
            linv[m][r] = 1.0f / __shfl(lsum[m], lg*4 + r);

    #pragma unroll
    for (int m = 0; m < 2; ++m)
        #pragma unroll
        for (int dt = 0; dt < 4; ++dt)
            #pragma unroll
            for (int r = 0; r < 4; ++r) {
                float v = o[m][dt][r] * linv[m][r];
                int row = qb*128 + w*32 + m*16 + lg*4 + r;
                int col = h*HDIM + dt*16 + lq;
                attout[(size_t)(b*SEQ + row) * EMBED + col] = f2bf(v);
            }
}

// ---------------------------------------------------------------------------
extern "C" void kernel_launch(void* const* d_in, const int* in_sizes, int n_in,
                              void* d_out, int out_size, void* d_ws, size_t ws_size,
                              hipStream_t stream) {
    const float* x      = (const float*)d_in[0];
    const float* W_qkv  = (const float*)d_in[1];
    const float* b_qkv  = (const float*)d_in[2];
    const float* W_proj = (const float*)d_in[3];
    const float* b_proj = (const float*)d_in[4];
    float* out = (float*)d_out;

    const int M = BATCH * SEQ;   // 8192

    char* ws = (char*)d_ws;
    unsigned short* x_b    = (unsigned short*)(ws);                 // 16 MB
    unsigned short* wqkvT  = (unsigned short*)(ws + 16777216);      // 6 MB
    unsigned short* wprojT = (unsigned short*)(ws + 23068672);      // 2 MB
    unsigned short* qkv_b  = (unsigned short*)(ws + 25165824);      // 48 MB
    unsigned short* vt_b   = (unsigned short*)(ws + 75497472);      // 16 MB
    unsigned short* att_b  = (unsigned short*)(ws + 92274688);      // 16 MB

    cast_f32_bf16<<<dim3((M * EMBED) / 1024), 256, 0, stream>>>(x, x_b);
    transpose_cast<<<dim3(QKV_LD / 64, EMBED / 64), 256, 0, stream>>>(W_qkv, wqkvT, EMBED, QKV_LD);
    transpose_cast<<<dim3(EMBED / 64, EMBED / 64), 256, 0, stream>>>(W_proj, wprojT, EMBED, EMBED);

    gemm_bf16<true, true><<<dim3(QKV_LD / 128, M / 128), 256, 0, stream>>>(
        x_b, wqkvT, b_qkv, qkv_b, M, QKV_LD, EMBED);

    vt_kernel<<<dim3(SEQ / 64, BATCH * HEADS), 256, 0, stream>>>(qkv_b, vt_b);

    attn_mfma<<<dim3(SEQ / 128, BATCH * HEADS), 256, 0, stream>>>(qkv_b, vt_b, att_b);

    gemm_bf16<false, false><<<dim3(EMBED / 128, M / 128), 256, 0, stream>>>(
        att_b, wprojT, b_proj, out, M, EMBED, EMBED);
}

// Round 4
// 241.183 us; speedup vs baseline: 11.1418x; 1.0562x over previous
//
#include <hip/hip_runtime.h>

#define EMBED   1024
#define HEADS   16
#define HDIM    64
#define SEQ     2048
#define BATCH   4
#define QKV_LD  3072

typedef __attribute__((ext_vector_type(8))) short short8v;
typedef __attribute__((ext_vector_type(4))) float floatx4;
typedef __attribute__((ext_vector_type(4))) unsigned int uint4v;
typedef __attribute__((ext_vector_type(2))) unsigned int uint2v;

// log2(e)/8 : folded into Q so S comes out in base-2 units
#define QSCALE 0.18033688011112042f

__device__ __forceinline__ unsigned short f2bf(float f) {
    unsigned int u = __builtin_bit_cast(unsigned int, f);
    u += 0x7FFFu + ((u >> 16) & 1u);
    return (unsigned short)(u >> 16);
}

__device__ __forceinline__ float fast_exp2(float x) {
    float r;
    asm("v_exp_f32 %0, %1" : "=v"(r) : "v"(x));
    return r;
}
__device__ __forceinline__ unsigned int cvt_pk_bf16(float lo, float hi) {
    unsigned int r;
    asm("v_cvt_pk_bf16_f32 %0, %1, %2" : "=v"(r) : "v"(lo), "v"(hi));
    return r;
}
// async global->LDS, 16B per lane; LDS dest = wave-uniform base + lane*16
__device__ __forceinline__ void gload_lds16(const unsigned short* g, unsigned short* l) {
    __builtin_amdgcn_global_load_lds(
        (const __attribute__((address_space(1))) unsigned int*)g,
        (__attribute__((address_space(3))) unsigned int*)l, 16, 0, 0);
}

// ---------------------------------------------------------------------------
__global__ __launch_bounds__(256) void cast_f32_bf16(const float* __restrict__ in,
                                                     unsigned short* __restrict__ out) {
    int i = blockIdx.x * 256 + threadIdx.x;
    float4 v = ((const float4*)in)[i];
    unsigned short o[4] = { f2bf(v.x), f2bf(v.y), f2bf(v.z), f2bf(v.w) };
    ((uint2*)out)[i] = *(uint2*)o;
}

// ---------------------------------------------------------------------------
__global__ __launch_bounds__(256) void transpose_cast(const float* __restrict__ in,
                                                      unsigned short* __restrict__ out,
                                                      int K, int N) {
    __shared__ float T[64][65];
    const int k0 = blockIdx.y * 64, n0 = blockIdx.x * 64;
    const int t = threadIdx.x;
    #pragma unroll
    for (int i = 0; i < 4; ++i) {
        int s = i * 256 + t;
        int k = s >> 4, c4 = s & 15;
        float4 v = *(const float4*)(in + (size_t)(k0 + k) * N + n0 + c4 * 4);
        T[k][c4*4+0] = v.x; T[k][c4*4+1] = v.y; T[k][c4*4+2] = v.z; T[k][c4*4+3] = v.w;
    }
    __syncthreads();
    const int n = t >> 2, kc = (t & 3) * 16;
    unsigned short tmp[16];
    #pragma unroll
    for (int j = 0; j < 16; ++j) tmp[j] = f2bf(T[kc + j][n]);
    *(short8v*)(out + (size_t)(n0 + n) * K + k0 + kc)     = *(short8v*)&tmp[0];
    *(short8v*)(out + (size_t)(n0 + n) * K + k0 + kc + 8) = *(short8v*)&tmp[8];
}

// ---------------------------------------------------------------------------
__global__ __launch_bounds__(256) void vt_kernel(const unsigned short* __restrict__ qkvb,
                                                 unsigned short* __restrict__ vt) {
    const int bh = blockIdx.y, b = bh >> 4, h = bh & 15;
    const int n0 = blockIdx.x * 64;
    const int t = threadIdx.x;
    __shared__ __align__(16) unsigned short T[64][72];
    #pragma unroll
    for (int i = 0; i < 2; ++i) {
        int s = i * 256 + t;
        int n = s >> 3, c = s & 7;
        short8v v = *(const short8v*)(qkvb + (size_t)(b*SEQ + n0 + n) * QKV_LD + 2*EMBED + h*HDIM + c*8);
        *(short8v*)&T[n][c*8] = v;
    }
    __syncthreads();
    #pragma unroll
    for (int i = 0; i < 2; ++i) {
        int s = i * 256 + t;
        int d = s >> 3, c = s & 7;
        unsigned short tmp[8];
        #pragma unroll
        for (int j = 0; j < 8; ++j) tmp[j] = T[c*8 + j][d];
        *(short8v*)(vt + ((size_t)bh * HDIM + d) * SEQ + n0 + c*8) = *(short8v*)&tmp[0];
    }
}

// ---------------------------------------------------------------------------
// bf16 MFMA GEMM, 128x128x32 tile, 4 waves.  SCALE_Q: multiply cols < EMBED
// (the Q third of qkv) by QSCALE in the epilogue (exp2-fold for attention).
// ---------------------------------------------------------------------------
template<bool OUT_BF16, bool SCALE_Q>
__global__ __launch_bounds__(256) void gemm_bf16(const unsigned short* __restrict__ A,
                                                 const unsigned short* __restrict__ BT,
                                                 const float* __restrict__ bias,
                                                 void* __restrict__ Cout,
                                                 int M, int N, int K) {
    __shared__ __align__(16) unsigned short As[128 * 40];
    __shared__ __align__(16) unsigned short Bs[128 * 40];
    const int tid = threadIdx.x;
    const int lane = tid & 63;
    const int w = tid >> 6;
    const int wm = w >> 1, wn = w & 1;
    const int lq = lane & 15, lg = lane >> 4;
    const int row0 = blockIdx.y * 128;
    const int col0 = blockIdx.x * 128;

    floatx4 acc[4][4];
    #pragma unroll
    for (int i = 0; i < 4; ++i)
        #pragma unroll
        for (int j = 0; j < 4; ++j)
            acc[i][j] = (floatx4){0.f, 0.f, 0.f, 0.f};

    for (int k0 = 0; k0 < K; k0 += 32) {
        __syncthreads();
        #pragma unroll
        for (int i = 0; i < 2; ++i) {
            int s = i * 256 + tid;
            int r = s >> 2, c = s & 3;
            short8v va = *(const short8v*)(A  + (size_t)(row0 + r) * K + k0 + c * 8);
            short8v vb = *(const short8v*)(BT + (size_t)(col0 + r) * K + k0 + c * 8);
            *(short8v*)(As + r * 40 + c * 8) = va;
            *(short8v*)(Bs + r * 40 + c * 8) = vb;
        }
        __syncthreads();

        short8v af[4], bf[4];
        #pragma unroll
        for (int mi = 0; mi < 4; ++mi)
            af[mi] = *(const short8v*)(As + (wm*64 + mi*16 + lq) * 40 + lg * 8);
        #pragma unroll
        for (int ni = 0; ni < 4; ++ni)
            bf[ni] = *(const short8v*)(Bs + (wn*64 + ni*16 + lq) * 40 + lg * 8);
        __builtin_amdgcn_s_setprio(1);
        #pragma unroll
        for (int mi = 0; mi < 4; ++mi)
            #pragma unroll
            for (int ni = 0; ni < 4; ++ni)
                acc[mi][ni] = __builtin_amdgcn_mfma_f32_16x16x32_bf16(af[mi], bf[ni], acc[mi][ni], 0, 0, 0);
        __builtin_amdgcn_s_setprio(0);
    }

    #pragma unroll
    for (int mi = 0; mi < 4; ++mi) {
        #pragma unroll
        for (int ni = 0; ni < 4; ++ni) {
            int col = col0 + wn*64 + ni*16 + lq;
            float bv = bias[col];
            #pragma unroll
            for (int r = 0; r < 4; ++r) {
                int row = row0 + wm*64 + mi*16 + lg*4 + r;
                float v = acc[mi][ni][r] + bv;
                if constexpr (SCALE_Q) { if (col < EMBED) v *= QSCALE; }
                if constexpr (OUT_BF16)
                    ((unsigned short*)Cout)[(size_t)row * N + col] = f2bf(v);
                else
                    ((float*)Cout)[(size_t)row * N + col] = v;
            }
        }
    }
}

// ---------------------------------------------------------------------------
// MFMA flash attention, swapped-QK^T + pi-permuted PV (no P LDS at all).
// Grid (16 q-blocks, 64 bh), 256 threads = 4 waves, 32 q-rows/wave.
// S^T = mfma(K, Q): lane owns q-col lq; k rows n*16+lg*4+r.
// PV uses k-permutation pi(8lg+j) = 16*(j>=4) + 4lg + (j&3) applied to BOTH
// P (A-frag == lane's own sacc, cvt_pk'd) and V (two b64 reads per frag).
// K/V staged via global_load_lds into double-buffered linear [64][64] tiles;
// source chunks XOR-swizzled (c ^= row&7) so frag reads are conflict-free.
// One __syncthreads per tile.  lsum cross-lane reduce deferred to epilogue.
// ---------------------------------------------------------------------------
__global__ __launch_bounds__(256) void attn_mfma(const unsigned short* __restrict__ qkvb,
                                                 const unsigned short* __restrict__ vt,
                                                 unsigned short* __restrict__ attout) {
    const int bh = blockIdx.y, b = bh >> 4, h = bh & 15;
    const int qb = blockIdx.x;
    const int tid = threadIdx.x;
    const int lane = tid & 63;
    const int w = tid >> 6;
    const int lq = lane & 15, lg = lane >> 4;
    const int rb = lq & 7;

    __shared__ __align__(16) unsigned short Ks[2][64 * 64];
    __shared__ __align__(16) unsigned short Vs[2][64 * 64];

    // Q fragments (pre-scaled by QSCALE inside the QKV GEMM)
    short8v qf[2][2];
    const unsigned short* qbase = qkvb + (size_t)(b*SEQ + qb*128 + w*32) * QKV_LD + h*HDIM;
    #pragma unroll
    for (int m = 0; m < 2; ++m)
        #pragma unroll
        for (int ks = 0; ks < 2; ++ks)
            qf[m][ks] = *(const short8v*)(qbase + (size_t)(m*16 + lq) * QKV_LD + ks*32 + lg*8);

    floatx4 o[2][4];
    #pragma unroll
    for (int m = 0; m < 2; ++m)
        #pragma unroll
        for (int dt = 0; dt < 4; ++dt)
            o[m][dt] = (floatx4){0.f, 0.f, 0.f, 0.f};
    float mr[2] = { -1e30f, -1e30f };
    float lsum[2] = { 0.f, 0.f };

    const unsigned short* kbase = qkvb + (size_t)(b*SEQ) * QKV_LD + EMBED + h*HDIM;
    const unsigned short* vbase = vt + (size_t)bh * HDIM * SEQ;

    // staging: thread covers chunks s = (w*2+q)*64 + lane, q=0,1
    // LDS(row, cl) = Global(row, cl ^ (row&7))
    const int s0 = (w*2 + 0)*64 + lane;
    const int s1 = (w*2 + 1)*64 + lane;
    const int r0 = s0 >> 3, c0 = (s0 & 7) ^ (r0 & 7);
    const int r1 = s1 >> 3, c1 = (s1 & 7) ^ (r1 & 7);

    const int NT = SEQ / 64;

    // prologue: stage tile 0 into buffer 0
    {
        gload_lds16(kbase + (size_t)r0 * QKV_LD + c0*8, &Ks[0][0] + (w*2+0)*512);
        gload_lds16(kbase + (size_t)r1 * QKV_LD + c1*8, &Ks[0][0] + (w*2+1)*512);
        gload_lds16(vbase + (size_t)r0 * SEQ + c0*8,    &Vs[0][0] + (w*2+0)*512);
        gload_lds16(vbase + (size_t)r1 * SEQ + c1*8,    &Vs[0][0] + (w*2+1)*512);
    }

    for (int kt = 0; kt < NT; ++kt) {
        const int cur = kt & 1;
        __syncthreads();   // drains this wave's async loads of tile kt + epoch sync

        if (kt + 1 < NT) {
            const unsigned short* kb = kbase + (size_t)(kt + 1) * 64 * QKV_LD;
            const unsigned short* vb = vbase + (kt + 1) * 64;
            unsigned short* dk = &Ks[cur ^ 1][0];
            unsigned short* dv = &Vs[cur ^ 1][0];
            gload_lds16(kb + (size_t)r0 * QKV_LD + c0*8, dk + (w*2+0)*512);
            gload_lds16(kb + (size_t)r1 * QKV_LD + c1*8, dk + (w*2+1)*512);
            gload_lds16(vb + (size_t)r0 * SEQ + c0*8,    dv + (w*2+0)*512);
            gload_lds16(vb + (size_t)r1 * SEQ + c1*8,    dv + (w*2+1)*512);
        }

        const unsigned short* Kc = &Ks[cur][0];
        const unsigned short* Vc = &Vs[cur][0];

        // ---- S^T = K @ Q^T : sacc[m][n][r] = S[k = n*16+lg*4+r][q = m*16+lq]
        floatx4 sacc[2][4];
        #pragma unroll
        for (int n = 0; n < 4; ++n) {
            const unsigned short* krow = Kc + (n*16 + lq) * 64;
            short8v kf0 = *(const short8v*)(krow + ((0*4 + lg) ^ rb) * 8);
            short8v kf1 = *(const short8v*)(krow + ((1*4 + lg) ^ rb) * 8);
            __builtin_amdgcn_s_setprio(1);
            #pragma unroll
            for (int m = 0; m < 2; ++m) {
                floatx4 z = (floatx4){0.f, 0.f, 0.f, 0.f};
                z = __builtin_amdgcn_mfma_f32_16x16x32_bf16(kf0, qf[m][0], z, 0, 0, 0);
                sacc[m][n] = __builtin_amdgcn_mfma_f32_16x16x32_bf16(kf1, qf[m][1], z, 0, 0, 0);
            }
            __builtin_amdgcn_s_setprio(0);
        }

        // ---- row max (lane-local 16 + lg-group reduce) ----
        float pm[2];
        #pragma unroll
        for (int m = 0; m < 2; ++m) {
            float v = fmaxf(fmaxf(sacc[m][0][0], sacc[m][0][1]),
                            fmaxf(sacc[m][0][2], sacc[m][0][3]));
            #pragma unroll
            for (int n = 1; n < 4; ++n)
                v = fmaxf(v, fmaxf(fmaxf(sacc[m][n][0], sacc[m][n][1]),
                                   fmaxf(sacc[m][n][2], sacc[m][n][3])));
            v = fmaxf(v, __shfl_xor(v, 16));
            v = fmaxf(v, __shfl_xor(v, 32));
            pm[m] = v;
        }

        // ---- defer-max rescale ----
        int need = (pm[0] > mr[0] + 8.f) | (pm[1] > mr[1] + 8.f);
        if (__any(need)) {
            #pragma unroll
            for (int m = 0; m < 2; ++m) {
                float mnew = fmaxf(mr[m], pm[m]);
                float alpha = fast_exp2(mr[m] - mnew);
                mr[m] = mnew;
                lsum[m] *= alpha;
                #pragma unroll
                for (int r = 0; r < 4; ++r) {
                    float a = __shfl(alpha, lg*4 + r);
                    #pragma unroll
                    for (int dt = 0; dt < 4; ++dt) o[m][dt][r] *= a;
                }
            }
        }

        // ---- P = exp2(S - m); pack directly into pi-permuted A-frags ----
        uint4v afu[2][2];
        #pragma unroll
        for (int m = 0; m < 2; ++m) {
            float psum = 0.f;
            unsigned int pk[4][2];
            #pragma unroll
            for (int n = 0; n < 4; ++n) {
                float p0 = fast_exp2(sacc[m][n][0] - mr[m]);
                float p1 = fast_exp2(sacc[m][n][1] - mr[m]);
                float p2 = fast_exp2(sacc[m][n][2] - mr[m]);
                float p3 = fast_exp2(sacc[m][n][3] - mr[m]);
                psum += (p0 + p1) + (p2 + p3);
                pk[n][0] = cvt_pk_bf16(p0, p1);
                pk[n][1] = cvt_pk_bf16(p2, p3);
            }
            lsum[m] += psum;   // lane-partial; cross-lane reduce deferred
            afu[m][0] = (uint4v){ pk[0][0], pk[0][1], pk[1][0], pk[1][1] };
            afu[m][1] = (uint4v){ pk[2][0], pk[2][1], pk[3][0], pk[3][1] };
        }

        // ---- O += P @ V (pi-permuted V B-frags: two b64 per frag) ----
        #pragma unroll
        for (int dt = 0; dt < 4; ++dt) {
            const unsigned short* vrow = Vc + (dt*16 + lq) * 64;
            #pragma unroll
            for (int nt = 0; nt < 2; ++nt) {
                int cA = (nt*4 + (lg >> 1)) ^ rb;
                int cB = (nt*4 + 2 + (lg >> 1)) ^ rb;
                int off = (lg & 1) * 4;
                uint2v vA = *(const uint2v*)(vrow + cA*8 + off);
                uint2v vB = *(const uint2v*)(vrow + cB*8 + off);
                uint4v tv = (uint4v){ vA[0], vA[1], vB[0], vB[1] };
                short8v vf = __builtin_bit_cast(short8v, tv);
                __builtin_amdgcn_s_setprio(1);
                #pragma unroll
                for (int m = 0; m < 2; ++m)
                    o[m][dt] = __builtin_amdgcn_mfma_f32_16x16x32_bf16(
                        __builtin_bit_cast(short8v, afu[m][nt]), vf, o[m][dt], 0, 0, 0);
                __builtin_amdgcn_s_setprio(0);
            }
        }
    }

    // ---- deferred lsum cross-lane reduce ----
    #pragma unroll
    for (int m = 0; m < 2; ++m) {
        lsum[m] += __shfl_xor(lsum[m], 16);
        lsum[m] += __shfl_xor(lsum[m], 32);
    }

    // ---- epilogue ----
    float linv[2][4];
    #pragma unroll
    for (int m = 0; m < 2; ++m)
        #pragma unroll
        for (int r = 0; r < 4; ++r)
            linv[m][r] = 1.0f / __shfl(lsum[m], lg*4 + r);

    #pragma unroll
    for (int m = 0; m < 2; ++m)
        #pragma unroll
        for (int dt = 0; dt < 4; ++dt)
            #pragma unroll
            for (int r = 0; r < 4; ++r) {
                float v = o[m][dt][r] * linv[m][r];
                int row = qb*128 + w*32 + m*16 + lg*4 + r;
                int col = h*HDIM + dt*16 + lq;
                attout[(size_t)(b*SEQ + row) * EMBED + col] = f2bf(v);
            }
}

// ---------------------------------------------------------------------------
extern "C" void kernel_launch(void* const* d_in, const int* in_sizes, int n_in,
                              void* d_out, int out_size, void* d_ws, size_t ws_size,
                              hipStream_t stream) {
    const float* x      = (const float*)d_in[0];
    const float* W_qkv  = (const float*)d_in[1];
    const float* b_qkv  = (const float*)d_in[2];
    const float* W_proj = (const float*)d_in[3];
    const float* b_proj = (const float*)d_in[4];
    float* out = (float*)d_out;

    const int M = BATCH * SEQ;   // 8192

    char* ws = (char*)d_ws;
    unsigned short* x_b    = (unsigned short*)(ws);                 // 16 MB
    unsigned short* wqkvT  = (unsigned short*)(ws + 16777216);      // 6 MB
    unsigned short* wprojT = (unsigned short*)(ws + 23068672);      // 2 MB
    unsigned short* qkv_b  = (unsigned short*)(ws + 25165824);      // 48 MB
    unsigned short* vt_b   = (unsigned short*)(ws + 75497472);      // 16 MB
    unsigned short* att_b  = (unsigned short*)(ws + 92274688);      // 16 MB

    cast_f32_bf16<<<dim3((M * EMBED) / 1024), 256, 0, stream>>>(x, x_b);
    transpose_cast<<<dim3(QKV_LD / 64, EMBED / 64), 256, 0, stream>>>(W_qkv, wqkvT, EMBED, QKV_LD);
    transpose_cast<<<dim3(EMBED / 64, EMBED / 64), 256, 0, stream>>>(W_proj, wprojT, EMBED, EMBED);

    gemm_bf16<true, true><<<dim3(QKV_LD / 128, M / 128), 256, 0, stream>>>(
        x_b, wqkvT, b_qkv, qkv_b, M, QKV_LD, EMBED);

    vt_kernel<<<dim3(SEQ / 64, BATCH * HEADS), 256, 0, stream>>>(qkv_b, vt_b);

    attn_mfma<<<dim3(SEQ / 128, BATCH * HEADS), 256, 0, stream>>>(qkv_b, vt_b, att_b);

    gemm_bf16<false, false><<<dim3(EMBED / 128, M / 128), 256, 0, stream>>>(
        att_b, wprojT, b_proj, out, M, EMBED, EMBED);
}

// Round 5
// 236.861 us; speedup vs baseline: 11.3451x; 1.0182x over previous
//
#include <hip/hip_runtime.h>

#define EMBED   1024
#define HEADS   16
#define HDIM    64
#define SEQ     2048
#define BATCH   4
#define QKV_LD  3072

typedef __attribute__((ext_vector_type(8))) short short8v;
typedef __attribute__((ext_vector_type(4))) float floatx4;
typedef __attribute__((ext_vector_type(4))) unsigned int uint4v;

// log2(e)/8 : folded into Q so S comes out in base-2 units
#define QSCALE 0.18033688011112042f

__device__ __forceinline__ unsigned short f2bf(float f) {
    unsigned int u = __builtin_bit_cast(unsigned int, f);
    u += 0x7FFFu + ((u >> 16) & 1u);
    return (unsigned short)(u >> 16);
}

__device__ __forceinline__ float fast_exp2(float x) {
    float r;
    asm("v_exp_f32 %0, %1" : "=v"(r) : "v"(x));
    return r;
}
__device__ __forceinline__ unsigned int cvt_pk_bf16(float lo, float hi) {
    unsigned int r;
    asm("v_cvt_pk_bf16_f32 %0, %1, %2" : "=v"(r) : "v"(lo), "v"(hi));
    return r;
}
// async global->LDS, 16B per lane; LDS dest = wave-uniform base + lane*16
__device__ __forceinline__ void gload_lds16(const unsigned short* g, unsigned short* l) {
    __builtin_amdgcn_global_load_lds(
        (const __attribute__((address_space(1))) unsigned int*)g,
        (__attribute__((address_space(3))) unsigned int*)l, 16, 0, 0);
}

// ---------------------------------------------------------------------------
__global__ __launch_bounds__(256) void cast_f32_bf16(const float* __restrict__ in,
                                                     unsigned short* __restrict__ out) {
    int i = blockIdx.x * 256 + threadIdx.x;
    float4 v = ((const float4*)in)[i];
    unsigned short o[4] = { f2bf(v.x), f2bf(v.y), f2bf(v.z), f2bf(v.w) };
    ((uint2*)out)[i] = *(uint2*)o;
}

// ---------------------------------------------------------------------------
__global__ __launch_bounds__(256) void transpose_cast(const float* __restrict__ in,
                                                      unsigned short* __restrict__ out,
                                                      int K, int N) {
    __shared__ float T[64][65];
    const int k0 = blockIdx.y * 64, n0 = blockIdx.x * 64;
    const int t = threadIdx.x;
    #pragma unroll
    for (int i = 0; i < 4; ++i) {
        int s = i * 256 + t;
        int k = s >> 4, c4 = s & 15;
        float4 v = *(const float4*)(in + (size_t)(k0 + k) * N + n0 + c4 * 4);
        T[k][c4*4+0] = v.x; T[k][c4*4+1] = v.y; T[k][c4*4+2] = v.z; T[k][c4*4+3] = v.w;
    }
    __syncthreads();
    const int n = t >> 2, kc = (t & 3) * 16;
    unsigned short tmp[16];
    #pragma unroll
    for (int j = 0; j < 16; ++j) tmp[j] = f2bf(T[kc + j][n]);
    *(short8v*)(out + (size_t)(n0 + n) * K + k0 + kc)     = *(short8v*)&tmp[0];
    *(short8v*)(out + (size_t)(n0 + n) * K + k0 + kc + 8) = *(short8v*)&tmp[8];
}

// ---------------------------------------------------------------------------
// V slice of qkv_b -> vt [bh][d][kv-permuted].  Within each 64-kv tile the
// columns are stored interleaved+swizzled so the attention PV B-fragment is a
// single conflict-free ds_read_b128:
//   position (d, chunk cp, j) holds V[kv = (c>>2)*32 + 16*(j>=4) + (c&3)*4 + (j&3)][d]
//   with c = cp ^ (d&7).
// ---------------------------------------------------------------------------
__global__ __launch_bounds__(256) void vt_kernel(const unsigned short* __restrict__ qkvb,
                                                 unsigned short* __restrict__ vt) {
    const int bh = blockIdx.y, b = bh >> 4, h = bh & 15;
    const int n0 = blockIdx.x * 64;
    const int t = threadIdx.x;
    __shared__ __align__(16) unsigned short T[64][72];
    #pragma unroll
    for (int i = 0; i < 2; ++i) {
        int s = i * 256 + t;
        int n = s >> 3, c = s & 7;
        short8v v = *(const short8v*)(qkvb + (size_t)(b*SEQ + n0 + n) * QKV_LD + 2*EMBED + h*HDIM + c*8);
        *(short8v*)&T[n][c*8] = v;
    }
    __syncthreads();
    #pragma unroll
    for (int i = 0; i < 2; ++i) {
        int s = i * 256 + t;
        int d = s >> 3, cp = s & 7;
        int c = cp ^ (d & 7);
        int base = (c >> 2) * 32 + (c & 3) * 4;
        unsigned short tmp[8];
        #pragma unroll
        for (int j = 0; j < 8; ++j)
            tmp[j] = T[base + ((j >> 2) << 4) + (j & 3)][d];
        *(short8v*)(vt + ((size_t)bh * HDIM + d) * SEQ + n0 + cp*8) = *(short8v*)&tmp[0];
    }
}

// ---------------------------------------------------------------------------
// bf16 MFMA GEMM, 128x128x32 tile, 4 waves.  SCALE_Q: multiply cols < EMBED
// (the Q third of qkv) by QSCALE in the epilogue (exp2-fold for attention).
// ---------------------------------------------------------------------------
template<bool OUT_BF16, bool SCALE_Q>
__global__ __launch_bounds__(256) void gemm_bf16(const unsigned short* __restrict__ A,
                                                 const unsigned short* __restrict__ BT,
                                                 const float* __restrict__ bias,
                                                 void* __restrict__ Cout,
                                                 int M, int N, int K) {
    __shared__ __align__(16) unsigned short As[128 * 40];
    __shared__ __align__(16) unsigned short Bs[128 * 40];
    const int tid = threadIdx.x;
    const int lane = tid & 63;
    const int w = tid >> 6;
    const int wm = w >> 1, wn = w & 1;
    const int lq = lane & 15, lg = lane >> 4;
    const int row0 = blockIdx.y * 128;
    const int col0 = blockIdx.x * 128;

    floatx4 acc[4][4];
    #pragma unroll
    for (int i = 0; i < 4; ++i)
        #pragma unroll
        for (int j = 0; j < 4; ++j)
            acc[i][j] = (floatx4){0.f, 0.f, 0.f, 0.f};

    for (int k0 = 0; k0 < K; k0 += 32) {
        __syncthreads();
        #pragma unroll
        for (int i = 0; i < 2; ++i) {
            int s = i * 256 + tid;
            int r = s >> 2, c = s & 3;
            short8v va = *(const short8v*)(A  + (size_t)(row0 + r) * K + k0 + c * 8);
            short8v vb = *(const short8v*)(BT + (size_t)(col0 + r) * K + k0 + c * 8);
            *(short8v*)(As + r * 40 + c * 8) = va;
            *(short8v*)(Bs + r * 40 + c * 8) = vb;
        }
        __syncthreads();

        short8v af[4], bf[4];
        #pragma unroll
        for (int mi = 0; mi < 4; ++mi)
            af[mi] = *(const short8v*)(As + (wm*64 + mi*16 + lq) * 40 + lg * 8);
        #pragma unroll
        for (int ni = 0; ni < 4; ++ni)
            bf[ni] = *(const short8v*)(Bs + (wn*64 + ni*16 + lq) * 40 + lg * 8);
        __builtin_amdgcn_s_setprio(1);
        #pragma unroll
        for (int mi = 0; mi < 4; ++mi)
            #pragma unroll
            for (int ni = 0; ni < 4; ++ni)
                acc[mi][ni] = __builtin_amdgcn_mfma_f32_16x16x32_bf16(af[mi], bf[ni], acc[mi][ni], 0, 0, 0);
        __builtin_amdgcn_s_setprio(0);
    }

    #pragma unroll
    for (int mi = 0; mi < 4; ++mi) {
        #pragma unroll
        for (int ni = 0; ni < 4; ++ni) {
            int col = col0 + wn*64 + ni*16 + lq;
            float bv = bias[col];
            #pragma unroll
            for (int r = 0; r < 4; ++r) {
                int row = row0 + wm*64 + mi*16 + lg*4 + r;
                float v = acc[mi][ni][r] + bv;
                if constexpr (SCALE_Q) { if (col < EMBED) v *= QSCALE; }
                if constexpr (OUT_BF16)
                    ((unsigned short*)Cout)[(size_t)row * N + col] = f2bf(v);
                else
                    ((float*)Cout)[(size_t)row * N + col] = v;
            }
        }
    }
}

// ---------------------------------------------------------------------------
// MFMA flash attention: swapped QK^T, pi-permuted PV (no P LDS), 3-buffer
// K/V with 2-tile-deep global_load_lds prefetch and counted vmcnt (never 0
// in steady state), raw s_barrier, XCD-aware block remap.
// ---------------------------------------------------------------------------
__global__ __launch_bounds__(256) void attn_mfma(const unsigned short* __restrict__ qkvb,
                                                 const unsigned short* __restrict__ vt,
                                                 unsigned short* __restrict__ attout) {
    // XCD remap: flat%8 picks XCD; give each XCD 8 whole bh (16 q-blocks each)
    const int flat = blockIdx.y * 16 + blockIdx.x;
    const int kk = flat >> 3;
    const int bh = (flat & 7) * 8 + (kk >> 4);
    const int qb = kk & 15;
    const int b = bh >> 4, h = bh & 15;
    const int tid = threadIdx.x;
    const int lane = tid & 63;
    const int w = tid >> 6;
    const int lq = lane & 15, lg = lane >> 4;
    const int rb = lq & 7;

    __shared__ __align__(16) unsigned short Ks[3][64 * 64];
    __shared__ __align__(16) unsigned short Vs[3][64 * 64];

    // Q fragments first (oldest vmcnt entries; retired by compiler's own wait)
    short8v qf[2][2];
    const unsigned short* qbase = qkvb + (size_t)(b*SEQ + qb*128 + w*32) * QKV_LD + h*HDIM;
    #pragma unroll
    for (int m = 0; m < 2; ++m)
        #pragma unroll
        for (int ks = 0; ks < 2; ++ks)
            qf[m][ks] = *(const short8v*)(qbase + (size_t)(m*16 + lq) * QKV_LD + ks*32 + lg*8);

    floatx4 o[2][4];
    #pragma unroll
    for (int m = 0; m < 2; ++m)
        #pragma unroll
        for (int dt = 0; dt < 4; ++dt)
            o[m][dt] = (floatx4){0.f, 0.f, 0.f, 0.f};
    float mr[2] = { -1e30f, -1e30f };
    float lsum[2] = { 0.f, 0.f };

    const unsigned short* kbase = qkvb + (size_t)(b*SEQ) * QKV_LD + EMBED + h*HDIM;
    const unsigned short* vbase = vt + (size_t)bh * HDIM * SEQ;

    // staging: this thread covers 16B chunks s0, s1 of the 512-chunk tile
    const int s0 = w*128 + lane, s1 = s0 + 64;
    const int r0 = s0 >> 3, r1 = s1 >> 3;
    const int ck0 = (s0 & 7) ^ (r0 & 7), ck1 = (s1 & 7) ^ (r1 & 7);  // K src swizzle
    const int cv0 = s0 & 7, cv1 = s1 & 7;                            // V pre-permuted

#define STAGE(T_, BUF_) do {                                                       \
        const unsigned short* kb_ = kbase + (size_t)(T_) * 64 * QKV_LD;            \
        const unsigned short* vb_ = vbase + (T_) * 64;                             \
        gload_lds16(kb_ + (size_t)r0 * QKV_LD + ck0*8, &Ks[BUF_][(w*2+0)*512]);    \
        gload_lds16(kb_ + (size_t)r1 * QKV_LD + ck1*8, &Ks[BUF_][(w*2+1)*512]);    \
        gload_lds16(vb_ + (size_t)r0 * SEQ + cv0*8,    &Vs[BUF_][(w*2+0)*512]);    \
        gload_lds16(vb_ + (size_t)r1 * SEQ + cv1*8,    &Vs[BUF_][(w*2+1)*512]);    \
    } while (0)

    const int NT = SEQ / 64;
    STAGE(0, 0);
    STAGE(1, 1);

    int cur = 0;
    for (int kt = 0; kt < NT; ++kt) {
        // tile kt's 4 loads are older than tile kt+1's 4 still in flight
        if (kt < NT - 1) asm volatile("s_waitcnt vmcnt(4)" ::: "memory");
        else             asm volatile("s_waitcnt vmcnt(0)" ::: "memory");
        __builtin_amdgcn_s_barrier();
        __builtin_amdgcn_sched_barrier(0);

        if (kt + 2 < NT) {
            int nb = cur + 2; if (nb >= 3) nb -= 3;
            STAGE(kt + 2, nb);
        }

        const unsigned short* Kc = &Ks[cur][0];
        const unsigned short* Vc = &Vs[cur][0];

        // ---- S^T = K @ Q^T : sacc[m][n][r] = S[k = n*16+lg*4+r][q = m*16+lq]
        floatx4 sacc[2][4];
        #pragma unroll
        for (int n = 0; n < 4; ++n) {
            const unsigned short* krow = Kc + (n*16 + lq) * 64;
            short8v kf0 = *(const short8v*)(krow + ((0*4 + lg) ^ rb) * 8);
            short8v kf1 = *(const short8v*)(krow + ((1*4 + lg) ^ rb) * 8);
            __builtin_amdgcn_s_setprio(1);
            #pragma unroll
            for (int m = 0; m < 2; ++m) {
                floatx4 z = (floatx4){0.f, 0.f, 0.f, 0.f};
                z = __builtin_amdgcn_mfma_f32_16x16x32_bf16(kf0, qf[m][0], z, 0, 0, 0);
                sacc[m][n] = __builtin_amdgcn_mfma_f32_16x16x32_bf16(kf1, qf[m][1], z, 0, 0, 0);
            }
            __builtin_amdgcn_s_setprio(0);
        }

        // ---- row max ----
        float pm[2];
        #pragma unroll
        for (int m = 0; m < 2; ++m) {
            float v = fmaxf(fmaxf(sacc[m][0][0], sacc[m][0][1]),
                            fmaxf(sacc[m][0][2], sacc[m][0][3]));
            #pragma unroll
            for (int n = 1; n < 4; ++n)
                v = fmaxf(v, fmaxf(fmaxf(sacc[m][n][0], sacc[m][n][1]),
                                   fmaxf(sacc[m][n][2], sacc[m][n][3])));
            v = fmaxf(v, __shfl_xor(v, 16));
            v = fmaxf(v, __shfl_xor(v, 32));
            pm[m] = v;
        }

        // ---- defer-max rescale ----
        int need = (pm[0] > mr[0] + 8.f) | (pm[1] > mr[1] + 8.f);
        if (__any(need)) {
            #pragma unroll
            for (int m = 0; m < 2; ++m) {
                float mnew = fmaxf(mr[m], pm[m]);
                float alpha = fast_exp2(mr[m] - mnew);
                mr[m] = mnew;
                lsum[m] *= alpha;
                #pragma unroll
                for (int r = 0; r < 4; ++r) {
                    float a = __shfl(alpha, lg*4 + r);
                    #pragma unroll
                    for (int dt = 0; dt < 4; ++dt) o[m][dt][r] *= a;
                }
            }
        }

        // ---- P = exp2(S - m); pack into pi-permuted A-frags (in-register) ----
        uint4v afu[2][2];
        #pragma unroll
        for (int m = 0; m < 2; ++m) {
            float psum = 0.f;
            unsigned int pk[4][2];
            #pragma unroll
            for (int n = 0; n < 4; ++n) {
                float p0 = fast_exp2(sacc[m][n][0] - mr[m]);
                float p1 = fast_exp2(sacc[m][n][1] - mr[m]);
                float p2 = fast_exp2(sacc[m][n][2] - mr[m]);
                float p3 = fast_exp2(sacc[m][n][3] - mr[m]);
                psum += (p0 + p1) + (p2 + p3);
                pk[n][0] = cvt_pk_bf16(p0, p1);
                pk[n][1] = cvt_pk_bf16(p2, p3);
            }
            lsum[m] += psum;   // lane-partial; cross-lane reduce deferred
            afu[m][0] = (uint4v){ pk[0][0], pk[0][1], pk[1][0], pk[1][1] };
            afu[m][1] = (uint4v){ pk[2][0], pk[2][1], pk[3][0], pk[3][1] };
        }

        // ---- O += P @ V (V B-frag = one swizzled b128 read) ----
        #pragma unroll
        for (int dt = 0; dt < 4; ++dt) {
            const unsigned short* vrow = Vc + (dt*16 + lq) * 64;
            #pragma unroll
            for (int nt = 0; nt < 2; ++nt) {
                short8v vf = *(const short8v*)(vrow + ((nt*4 + lg) ^ rb) * 8);
                __builtin_amdgcn_s_setprio(1);
                #pragma unroll
                for (int m = 0; m < 2; ++m)
                    o[m][dt] = __builtin_amdgcn_mfma_f32_16x16x32_bf16(
                        __builtin_bit_cast(short8v, afu[m][nt]), vf, o[m][dt], 0, 0, 0);
                __builtin_amdgcn_s_setprio(0);
            }
        }

        cur = (cur == 2) ? 0 : cur + 1;
    }
#undef STAGE

    // ---- deferred lsum cross-lane reduce ----
    #pragma unroll
    for (int m = 0; m < 2; ++m) {
        lsum[m] += __shfl_xor(lsum[m], 16);
        lsum[m] += __shfl_xor(lsum[m], 32);
    }

    float linv[2][4];
    #pragma unroll
    for (int m = 0; m < 2; ++m)
        #pragma unroll
        for (int r = 0; r < 4; ++r)
            linv[m][r] = 1.0f / __shfl(lsum[m], lg*4 + r);

    #pragma unroll
    for (int m = 0; m < 2; ++m)
        #pragma unroll
        for (int dt = 0; dt < 4; ++dt)
            #pragma unroll
            for (int r = 0; r < 4; ++r) {
                float v = o[m][dt][r] * linv[m][r];
                int row = qb*128 + w*32 + m*16 + lg*4 + r;
                int col = h*HDIM + dt*16 + lq;
                attout[(size_t)(b*SEQ + row) * EMBED + col] = f2bf(v);
            }
}

// ---------------------------------------------------------------------------
extern "C" void kernel_launch(void* const* d_in, const int* in_sizes, int n_in,
                              void* d_out, int out_size, void* d_ws, size_t ws_size,
                              hipStream_t stream) {
    const float* x      = (const float*)d_in[0];
    const float* W_qkv  = (const float*)d_in[1];
    const float* b_qkv  = (const float*)d_in[2];
    const float* W_proj = (const float*)d_in[3];
    const float* b_proj = (const float*)d_in[4];
    float* out = (float*)d_out;

    const int M = BATCH * SEQ;   // 8192

    char* ws = (char*)d_ws;
    unsigned short* x_b    = (unsigned short*)(ws);                 // 16 MB
    unsigned short* wqkvT  = (unsigned short*)(ws + 16777216);      // 6 MB
    unsigned short* wprojT = (unsigned short*)(ws + 23068672);      // 2 MB
    unsigned short* qkv_b  = (unsigned short*)(ws + 25165824);      // 48 MB
    unsigned short* vt_b   = (unsigned short*)(ws + 75497472);      // 16 MB
    unsigned short* att_b  = (unsigned short*)(ws + 92274688);      // 16 MB

    cast_f32_bf16<<<dim3((M * EMBED) / 1024), 256, 0, stream>>>(x, x_b);
    transpose_cast<<<dim3(QKV_LD / 64, EMBED / 64), 256, 0, stream>>>(W_qkv, wqkvT, EMBED, QKV_LD);
    transpose_cast<<<dim3(EMBED / 64, EMBED / 64), 256, 0, stream>>>(W_proj, wprojT, EMBED, EMBED);

    gemm_bf16<true, true><<<dim3(QKV_LD / 128, M / 128), 256, 0, stream>>>(
        x_b, wqkvT, b_qkv, qkv_b, M, QKV_LD, EMBED);

    vt_kernel<<<dim3(SEQ / 64, BATCH * HEADS), 256, 0, stream>>>(qkv_b, vt_b);

    attn_mfma<<<dim3(SEQ / 128, BATCH * HEADS), 256, 0, stream>>>(qkv_b, vt_b, att_b);

    gemm_bf16<false, false><<<dim3(EMBED / 128, M / 128), 256, 0, stream>>>(
        att_b, wprojT, b_proj, out, M, EMBED, EMBED);
}